// Round 5
// baseline (276611.841 us; speedup 1.0000x reference)
//
#include <hip/hip_runtime.h>
#include <math.h>

#define HH 2048
#define DD 66
#define TT 4096
#define PRE 64
#define NWG 256
#define RPW 8          // gate-rows per wave (4 gates x 2 h-rows)
#define FSTRIDE 16     // flag padding: 16 uints = 64B per WG

// ---- numeric representation -------------------------------------------------
// Weights stored as fp16(64*w) [VGPR] + int8 residual q = rint((64w - hi)*127*2^11)
// (residual of fp16 RTN at |64w|<=1.42 fits +-127 exactly). Explicit
// flush-to-zero of subnormal hi at ENCODE time so consumer fdot2 (which may
// flush subnormal inputs) agrees with the residual.
// h published as flush-aware fp16 hi + fp16((h-hi)*2048) lo.
// Gate = accf/64 + accl/(64*2048) + accr/(64*260096)  [fp32 fmaf]
#define S_HI 0.015625f
#define S_LO 7.62939453125e-06f
#define S_RS (1.0f / 16646144.0f)
#define RQ   260096.0f            // 127 * 2^11
#define F16_MIN_NORM 6.104e-05f

typedef _Float16 f16x2 __attribute__((ext_vector_type(2)));

#if defined(__HIP_DEVICE_COMPILE__) && __has_builtin(__builtin_amdgcn_fdot2)
#define FDOT2(a, b, c) __builtin_amdgcn_fdot2((a), (b), (c), false)
#else
#define FDOT2(a, b, c) fmaf((float)(a).y, (float)(b).y, fmaf((float)(a).x, (float)(b).x, (c)))
#endif

__device__ __forceinline__ f16x2 u2h(unsigned u) { return __builtin_bit_cast(f16x2, u); }

// int8x4 -> two f16x2 via magic-bias (vanilla ALU only; no sdot4, no v_perm)
__device__ __forceinline__ void unp8(unsigned u, f16x2& plo, f16x2& phi) {
  unsigned t0 = (u & 0x000000FFu) | ((u << 8) & 0x00FF0000u);
  unsigned t1 = ((u >> 16) & 0x000000FFu) | ((u >> 8) & 0x00FF0000u);
  t0 = (t0 ^ 0x00800080u) | 0x64006400u;   // 1152 + (b+... ) per half
  t1 = (t1 ^ 0x00800080u) | 0x64006400u;
  f16x2 K; K.x = (_Float16)1152.0f; K.y = (_Float16)1152.0f;
  plo = u2h(t0) - K;                        // v_pk_add_f16, exact integers
  phi = u2h(t1) - K;
}

__device__ __forceinline__ int q8(float x) {
  float s = x * RQ;
  s = fminf(fmaxf(s, -127.0f), 127.0f);
  return (int)rintf(s);
}

// split one float2 of raw weights -> fp16 hi pair (flush-aware) + 2 residual bytes
__device__ __forceinline__ unsigned splitw(float2 f, f16x2* hi) {
  float a = f.x * 64.0f, b = f.y * 64.0f;
  _Float16 ha = (_Float16)a, hb = (_Float16)b;
  float fa = (float)ha, fb = (float)hb;
  if (fabsf(fa) < F16_MIN_NORM) { ha = (_Float16)0.0f; fa = 0.0f; }
  if (fabsf(fb) < F16_MIN_NORM) { hb = (_Float16)0.0f; fb = 0.0f; }
  f16x2 h; h.x = ha; h.y = hb; *hi = h;
  int qa = q8(a - fa), qb = q8(b - fb);
  return (unsigned)(qa & 255) | ((unsigned)(qb & 255) << 8);
}

__device__ __forceinline__ void splith(float h0, float h1, unsigned* uhi, unsigned* ulo) {
  _Float16 a0 = (_Float16)h0, a1 = (_Float16)h1;
  float f0 = (float)a0, f1 = (float)a1;
  if (fabsf(f0) < F16_MIN_NORM) { a0 = (_Float16)0.0f; f0 = 0.0f; }
  if (fabsf(f1) < F16_MIN_NORM) { a1 = (_Float16)0.0f; f1 = 0.0f; }
  f16x2 hi; hi.x = a0; hi.y = a1;
  f16x2 lo; lo.x = (_Float16)((h0 - f0) * 2048.0f); lo.y = (_Float16)((h1 - f1) * 2048.0f);
  *uhi = __builtin_bit_cast(unsigned, hi);
  *ulo = __builtin_bit_cast(unsigned, lo);
}

__device__ __forceinline__ float sigm(float x) { return 1.0f / (1.0f + expf(-x)); }

// Spin barrier with watchdog: after ~2^20 polls arm abort; all waits then fall
// through so a deadlock TERMINATES (numeric fail w/ counters) instead of hanging.
__device__ __forceinline__ void gbar_wait(unsigned* flags, unsigned* abortw,
                                          int target, int tid) {
  int v = (int)__hip_atomic_load(&flags[tid * FSTRIDE], __ATOMIC_RELAXED, __HIP_MEMORY_SCOPE_AGENT);
  int ab = 0, n = 0;
  while (!__syncthreads_and((int)((v >= target) | ab))) {
    v = (int)__hip_atomic_load(&flags[tid * FSTRIDE], __ATOMIC_RELAXED, __HIP_MEMORY_SCOPE_AGENT);
    if (++n >= (1 << 13)) {
      if (n >= (1 << 20))
        __hip_atomic_store(abortw, 1u, __ATOMIC_RELAXED, __HIP_MEMORY_SCOPE_AGENT);
      ab = (__hip_atomic_load(abortw, __ATOMIC_RELAXED, __HIP_MEMORY_SCOPE_AGENT) == 1u);
    }
  }
}

// one matrix pass: fdot2 hi/lo + residual (RESEXPR yields the u32 for (r,k))
#define PASS(HBASE, WREG, RESEXPR)                                             \
  {                                                                            \
    _Pragma("unroll")                                                          \
    for (int half = 0; half < 2; ++half) {                                     \
      unsigned hh[8], hl[8];                                                   \
      _Pragma("unroll")                                                        \
      for (int jj = 0; jj < 8; ++jj) {                                         \
        int p = lane + 64 * (8 * half + jj);                                   \
        hh[jj] = __hip_atomic_load(&(HBASE)[2 * p],     __ATOMIC_RELAXED, __HIP_MEMORY_SCOPE_AGENT); \
        hl[jj] = __hip_atomic_load(&(HBASE)[2 * p + 1], __ATOMIC_RELAXED, __HIP_MEMORY_SCOPE_AGENT); \
      }                                                                        \
      _Pragma("unroll")                                                        \
      for (int r = 0; r < RPW; ++r) {                                          \
        _Pragma("unroll")                                                      \
        for (int jj = 0; jj < 8; ++jj) {                                       \
          int j = 8 * half + jj;                                               \
          accf[r] = FDOT2(WREG[r][j], u2h(hh[jj]), accf[r]);                   \
          accl[r] = FDOT2(WREG[r][j], u2h(hl[jj]), accl[r]);                   \
        }                                                                      \
        _Pragma("unroll")                                                      \
        for (int kk = 0; kk < 4; ++kk) {                                       \
          int k = 4 * half + kk;                                               \
          unsigned u = (RESEXPR);                                              \
          f16x2 plo, phi; unp8(u, plo, phi);                                   \
          accr[r] = FDOT2(plo, u2h(hh[2 * kk]),     accr[r]);                  \
          accr[r] = FDOT2(phi, u2h(hh[2 * kk + 1]), accr[r]);                  \
        }                                                                      \
      }                                                                        \
    }                                                                          \
  }

// prologue: one matrix -> fp16 hi regs + packed int8 residual via STORE
#define LOADW(WPTR, WREG, STORE)                                               \
  {                                                                            \
    _Pragma("unroll")                                                          \
    for (int r = 0; r < RPW; ++r) {                                            \
      const int gro = (r >> 1) * HH + rowbase + 2 * wave + (r & 1);            \
      const float2* src = (const float2*)((WPTR) + (size_t)gro * HH);          \
      _Pragma("unroll")                                                        \
      for (int k = 0; k < 8; ++k) {                                            \
        float2 f0 = src[lane + 64 * (2 * k)];                                  \
        float2 f1 = src[lane + 64 * (2 * k + 1)];                              \
        unsigned b01 = splitw(f0, &WREG[r][2 * k]);                            \
        unsigned b23 = splitw(f1, &WREG[r][2 * k + 1]);                        \
        unsigned pk = b01 | (b23 << 16);                                       \
        STORE;                                                                 \
      }                                                                        \
    }                                                                          \
  }

#define OUTBLK(SLOT, TOUT)                                                     \
  if (wg < DD) {                                                               \
    const float2* wrow = (const float2*)(Wlin + (size_t)wg * HH);              \
    float p = 0.0f;                                                            \
    _Pragma("unroll")                                                          \
    for (int i = 0; i < 4; ++i) {                                              \
      int P = tid + 256 * i;                                                   \
      unsigned uh = __hip_atomic_load(&h2px[(SLOT) * 2048 + 2 * P],     __ATOMIC_RELAXED, __HIP_MEMORY_SCOPE_AGENT); \
      unsigned ul = __hip_atomic_load(&h2px[(SLOT) * 2048 + 2 * P + 1], __ATOMIC_RELAXED, __HIP_MEMORY_SCOPE_AGENT); \
      f16x2 hhv = u2h(uh), hlv = u2h(ul);                                      \
      float2 wv = wrow[P];                                                     \
      float hx = fmaf((float)hlv.x, 4.8828125e-4f, (float)hhv.x);              \
      float hy = fmaf((float)hlv.y, 4.8828125e-4f, (float)hhv.y);              \
      p = fmaf(wv.x, hx, p); p = fmaf(wv.y, hy, p);                            \
    }                                                                          \
    _Pragma("unroll")                                                          \
    for (int sh = 32; sh > 0; sh >>= 1) p += __shfl_xor(p, sh, 64);            \
    if (lane == 0) {                                                           \
      if (wave == 0) p += blin[wg];                                            \
      atomicAdd(&out[(size_t)(TOUT) * DD + wg], p);                            \
    }                                                                          \
  }

__global__ __launch_bounds__(256, 1) void lstm_v5(
    const float* __restrict__ y,
    const float* __restrict__ Wih1, const float* __restrict__ Whh1,
    const float* __restrict__ bih1, const float* __restrict__ bhh1,
    const float* __restrict__ Wih2, const float* __restrict__ Whh2,
    const float* __restrict__ bih2, const float* __restrict__ bhh2,
    const float* __restrict__ Wlin, const float* __restrict__ blin,
    float* __restrict__ out,
    unsigned* h1px, unsigned* h2px,
    unsigned* flags1, unsigned* flags2, unsigned* abortw)
{
  // EXACTLY 131072 B static LDS (proven size on gfx950) — nothing else shared.
  __shared__ unsigned lds1[16384];   // Whh1 int8 residual: [32 rows][8 k][64 lane]
  __shared__ unsigned ldsb[16384];   // Whh2 int8 residual

  const int tid = threadIdx.x;
  const int wg = blockIdx.x;
  const int wave = tid >> 6;
  const int lane = tid & 63;
  const int rowbase = wg * RPW;           // 8 h-rows per WG
  const int P = wg * 4 + wave;            // this wave's h-pair (rows 2P, 2P+1)

  // persistent fp16 hi weights (384 VGPRs) + Wih2 residual in regs (64 VGPRs)
  f16x2 w1[RPW][16], wa[RPW][16], wb[RPW][16];
  unsigned wlo2[RPW][8];
  LOADW(Whh1, w1, (lds1[((wave * RPW + r) * 8 + k) * 64 + lane] = pk))
  LOADW(Wih2, wa, (wlo2[r][k] = pk))
  LOADW(Whh2, wb, (ldsb[((wave * RPW + r) * 8 + k) * 64 + lane] = pk))

  float c1v0 = 0.0f, c1v1 = 0.0f, c2v0 = 0.0f, c2v1 = 0.0f;  // lane0 c-state
  __syncthreads();

  #pragma unroll 1
  for (int t = 0; t < TT; ++t) {
    const int cur = t & 1, prv = cur ^ 1;

    //================ phase 1: layer-1 gates ================
    float xa = y[(size_t)t * DD + lane];
    float xb = (lane < DD - 64) ? y[(size_t)t * DD + 64 + lane] : 0.0f;
    float accf[RPW], accl[RPW], accr[RPW];
    #pragma unroll
    for (int r = 0; r < RPW; ++r) { accf[r] = 0.f; accl[r] = 0.f; accr[r] = 0.f; }

    if (t > 0) {  // h1_{t-1}; visibility established by t-1 phase-2 flags1 wait
      PASS((h1px + prv * 2048), w1, lds1[((wave * RPW + r) * 8 + k) * 64 + lane])
    }

    float gv[RPW];
    #pragma unroll
    for (int r = 0; r < RPW; ++r) {
      const int gro = (r >> 1) * HH + rowbase + 2 * wave + (r & 1);
      float a = fmaf(accr[r], S_RS, fmaf(accl[r], S_LO, accf[r] * S_HI));
      a = fmaf(Wih1[(size_t)gro * DD + lane], xa, a);
      if (lane < DD - 64) a = fmaf(Wih1[(size_t)gro * DD + 64 + lane], xb, a);
      #pragma unroll
      for (int sh = 32; sh > 0; sh >>= 1) a += __shfl_xor(a, sh, 64);
      gv[r] = a;
    }

    if (lane == 0) {
      float hv[2];
      #pragma unroll
      for (int q = 0; q < 2; ++q) {
        const int ro = rowbase + 2 * wave + q;
        float gi = sigm(gv[q]     + bih1[ro]          + bhh1[ro]);
        float gf = sigm(gv[2 + q] + bih1[HH + ro]     + bhh1[HH + ro]);
        float gg = tanhf(gv[4 + q] + bih1[2 * HH + ro] + bhh1[2 * HH + ro]);
        float go = sigm(gv[6 + q] + bih1[3 * HH + ro] + bhh1[3 * HH + ro]);
        float cp = (q == 0) ? c1v0 : c1v1;
        float c = fmaf(gf, cp, gi * gg);
        if (q == 0) c1v0 = c; else c1v1 = c;
        hv[q] = go * tanhf(c);
      }
      unsigned uhi, ulo; splith(hv[0], hv[1], &uhi, &ulo);
      __hip_atomic_store(&h1px[cur * 2048 + 2 * P],     uhi, __ATOMIC_RELAXED, __HIP_MEMORY_SCOPE_AGENT);
      __hip_atomic_store(&h1px[cur * 2048 + 2 * P + 1], ulo, __ATOMIC_RELAXED, __HIP_MEMORY_SCOPE_AGENT);
    }
    __syncthreads();  // all publishes drained before the release flag
    if (tid == 0)
      __hip_atomic_store(&flags1[wg * FSTRIDE], (unsigned)(t + 1),
                         __ATOMIC_RELEASE, __HIP_MEMORY_SCOPE_AGENT);

    //================ phase 2: layer-2 gates ================
    #pragma unroll
    for (int r = 0; r < RPW; ++r) { accf[r] = 0.f; accl[r] = 0.f; accr[r] = 0.f; }

    if (t > 0) {
      // deferred end-of-step barrier from t-1 (h2_{t-1} visibility + slot reuse)
      gbar_wait(flags2, abortw, t, tid);
      PASS((h2px + prv * 2048), wb, ldsb[((wave * RPW + r) * 8 + k) * 64 + lane])
    }

    gbar_wait(flags1, abortw, t + 1, tid);  // h1_t from all WGs
    PASS((h1px + cur * 2048), wa, wlo2[r][k])

    #pragma unroll
    for (int r = 0; r < RPW; ++r) {
      float a = fmaf(accr[r], S_RS, fmaf(accl[r], S_LO, accf[r] * S_HI));
      #pragma unroll
      for (int sh = 32; sh > 0; sh >>= 1) a += __shfl_xor(a, sh, 64);
      gv[r] = a;
    }

    if (lane == 0) {
      float hv[2];
      #pragma unroll
      for (int q = 0; q < 2; ++q) {
        const int ro = rowbase + 2 * wave + q;
        float gi = sigm(gv[q]     + bih2[ro]          + bhh2[ro]);
        float gf = sigm(gv[2 + q] + bih2[HH + ro]     + bhh2[HH + ro]);
        float gg = tanhf(gv[4 + q] + bih2[2 * HH + ro] + bhh2[2 * HH + ro]);
        float go = sigm(gv[6 + q] + bih2[3 * HH + ro] + bhh2[3 * HH + ro]);
        float cp = (q == 0) ? c2v0 : c2v1;
        float c = fmaf(gf, cp, gi * gg);
        if (q == 0) c2v0 = c; else c2v1 = c;
        hv[q] = go * tanhf(c);
      }
      unsigned uhi, ulo; splith(hv[0], hv[1], &uhi, &ulo);
      __hip_atomic_store(&h2px[cur * 2048 + 2 * P],     uhi, __ATOMIC_RELAXED, __HIP_MEMORY_SCOPE_AGENT);
      __hip_atomic_store(&h2px[cur * 2048 + 2 * P + 1], ulo, __ATOMIC_RELAXED, __HIP_MEMORY_SCOPE_AGENT);
    }
    __syncthreads();
    if (tid == 0)
      __hip_atomic_store(&flags2[wg * FSTRIDE], (unsigned)(t + 1),
                         __ATOMIC_RELEASE, __HIP_MEMORY_SCOPE_AGENT);

    // out_{t-1} = Wlin . h2_{t-1} + blin, overlapping the deferred barrier.
    // Slot prv safe: its next writer (phase2 of t+1) is gated by flags1(t+2),
    // which program-order-follows these loads (release drains them).
    if (t >= PRE + 1) { OUTBLK(prv, t - 1 - PRE) }
  }

  //================ epilogue: out for t = TT-1 ================
  gbar_wait(flags2, abortw, TT, tid);
  { OUTBLK(((TT - 1) & 1), TT - 1 - PRE) }
}

extern "C" void kernel_launch(void* const* d_in, const int* in_sizes, int n_in,
                              void* d_out, int out_size, void* d_ws, size_t ws_size,
                              hipStream_t stream) {
  const float* y    = (const float*)d_in[0];
  const float* Wih1 = (const float*)d_in[1];
  const float* Whh1 = (const float*)d_in[2];
  const float* bih1 = (const float*)d_in[3];
  const float* bhh1 = (const float*)d_in[4];
  const float* Wih2 = (const float*)d_in[5];
  const float* Whh2 = (const float*)d_in[6];
  const float* bih2 = (const float*)d_in[7];
  const float* bhh2 = (const float*)d_in[8];
  const float* Wlin = (const float*)d_in[9];
  const float* blin = (const float*)d_in[10];
  // d_in[11] = pre_output_len (64), compiled in as PRE.
  float* out = (float*)d_out;

  unsigned* ws = (unsigned*)d_ws;
  unsigned* h1px   = ws;                      // 4096 u32 (2 slots x 1024 pairs x hi/lo)
  unsigned* h2px   = h1px + 4096;             // 4096 u32
  unsigned* flags1 = h2px + 4096;             // 4096 u32
  unsigned* flags2 = flags1 + NWG * FSTRIDE;  // 4096 u32
  unsigned* abortw = flags2 + NWG * FSTRIDE;  // 1 u32

  void* args[] = { &y, &Wih1, &Whh1, &bih1, &bhh1, &Wih2, &Whh2, &bih2, &bhh2,
                   &Wlin, &blin, &out, &h1px, &h2px, &flags1, &flags2, &abortw };
  hipError_t e = hipLaunchCooperativeKernel((const void*)lstm_v5, dim3(NWG),
                                            dim3(256), args, 0, stream);
  if (e != hipSuccess) {
    // Fallback: regular launch. 256 blocks at 1 block/CU on 256 CUs are all
    // co-resident, so the flag protocol still completes; watchdog bounds a
    // pathological schedule.
    hipLaunchKernelGGL(lstm_v5, dim3(NWG), dim3(256), 0, stream,
                       y, Wih1, Whh1, bih1, bhh1, Wih2, Whh2, bih2, bhh2,
                       Wlin, blin, out, h1px, h2px, flags1, flags2, abortw);
  }
}